// Round 5
// baseline (584.969 us; speedup 1.0000x reference)
//
#include <hip/hip_runtime.h>
#include <math.h>

#define BINS 4096
#define CAP 4096
#define G 8
#define NT1 1024
#define NT2 256
#define NT3 1024

#define RMAX_F 0.9999999403953552f
#define RMAX_LOG_F -5.960464477539063e-08f
#define NEG_BIG -3.0e38f

__device__ __forceinline__ unsigned keyOf(float v) {
    unsigned b = __float_as_uint(v);
    return (b & 0x80000000u) ? ~b : (b | 0x80000000u);
}
__device__ __forceinline__ float valOfKey(unsigned k) {
    unsigned b = (k & 0x80000000u) ? (k ^ 0x80000000u) : ~k;
    return __uint_as_float(b);
}

// ---------------- K1: sampled histogram -> per-row threshold ----------------
__global__ __launch_bounds__(NT1) void k_thresh(
    const float* __restrict__ logits, const int* __restrict__ top_kv,
    unsigned* __restrict__ tloA, int* __restrict__ cntA, int V)
{
    const int r = blockIdx.x;
    const int tid = threadIdx.x;
    __shared__ unsigned hist[BINS * 2];
    __shared__ int scanI[NT1];
    __shared__ unsigned s_tlo;

    const float* row = logits + (long long)r * V;
    int k = top_kv[r];
    if (k < 1) k = 1;
    if (k > V) k = V;
    const float4* row4 = (const float4*)row;
    const int V4 = V >> 2;
    const unsigned cpy = tid & 1u;

    for (int i = tid; i < BINS * 2; i += NT1) hist[i] = 0;
    if (tid == 0) s_tlo = 0u;          // 0 => always-fallback signal
    __syncthreads();
    for (int i = tid; i < V4; i += NT1 * 8) {   // ~1/8 sample, coalesced chunks
        float4 l4 = row4[i];
        atomicAdd(&hist[((keyOf(l4.x) >> 20) << 1) | cpy], 1u);
        atomicAdd(&hist[((keyOf(l4.y) >> 20) << 1) | cpy], 1u);
        atomicAdd(&hist[((keyOf(l4.z) >> 20) << 1) | cpy], 1u);
        atomicAdd(&hist[((keyOf(l4.w) >> 20) << 1) | cpy], 1u);
    }
    __syncthreads();
    {
        int base = tid << 2;
        int cs = 0;
        #pragma unroll
        for (int j = 0; j < 4; ++j)
            cs += (int)(hist[(base + j) * 2] + hist[(base + j) * 2 + 1]);
        scanI[tid] = cs;
    }
    __syncthreads();
    for (int d = 1; d < NT1; d <<= 1) {         // suffix scan
        int v = (tid + d < NT1) ? scanI[tid + d] : 0;
        __syncthreads();
        scanI[tid] += v;
        __syncthreads();
    }
    const int S = scanI[0];
    long long ks = ((long long)k * S) / V;
    const int starg = (int)ks + 40 + (int)(ks >> 2);
    const bool ok = (starg >= 1) && (2 * starg <= S);
    if (ok) {
        int mine = scanI[tid];
        int above = (tid + 1 < NT1) ? scanI[tid + 1] : 0;
        if (mine >= starg && above < starg) {    // exactly one thread
            int base = tid << 2;
            int run = above;
            for (int b = base + 3; b >= base; --b) {
                int mb = (int)(hist[b * 2] + hist[b * 2 + 1]);
                if (run + mb >= starg) { s_tlo = (unsigned)b << 20; break; }
                run += mb;
            }
        }
    }
    __syncthreads();
    if (tid == 0) { tloA[r] = s_tlo; cntA[r] = 0; }
}

// ---------------- K2: parallel compaction into global candidate buffer ------
__global__ __launch_bounds__(NT2) void k_compact(
    const float* __restrict__ logits, const unsigned* __restrict__ tloA,
    int* __restrict__ cntA, unsigned long long* __restrict__ candg,
    int V, int capws)
{
    const int gb = blockIdx.x;
    const int r = gb >> 3;                       // G = 8
    const int s = gb & 7;
    const int tid = threadIdx.x;
    const int lane = tid & 63;

    const float* row = logits + (long long)r * V;
    const unsigned tlo = tloA[r];
    int* cnt = &cntA[r];
    unsigned long long* cbase = candg + (long long)r * capws;
    const float4* row4 = (const float4*)row;
    const int V4 = V >> 2;
    const int Vt = V4 << 2;

    auto emit = [&](unsigned key, unsigned gidx) {
        bool pred = (key >= tlo);
        unsigned long long mask = __ballot(pred ? 1 : 0);
        if (mask) {
            int leader = __ffsll(mask) - 1;
            int c = __popcll(mask);
            int base = 0;
            if (lane == leader) base = atomicAdd(cnt, c);
            base = __shfl(base, leader);
            if (pred) {
                int pos = base + __popcll(mask & ((1ULL << lane) - 1ULL));
                if (pos < capws)
                    cbase[pos] = ((unsigned long long)key << 32) | (unsigned)(~gidx);
            }
        }
    };
    auto procF4 = [&](float4 l4, int i4) {
        emit(keyOf(l4.x), (unsigned)(i4 * 4 + 0));
        emit(keyOf(l4.y), (unsigned)(i4 * 4 + 1));
        emit(keyOf(l4.z), (unsigned)(i4 * 4 + 2));
        emit(keyOf(l4.w), (unsigned)(i4 * 4 + 3));
    };

    const int stride = NT2 * G;
    int i = s * NT2 + tid;
    for (; i + 3 * stride < V4; i += 4 * stride) {
        float4 a0 = row4[i];
        float4 a1 = row4[i + stride];
        float4 a2 = row4[i + 2 * stride];
        float4 a3 = row4[i + 3 * stride];
        procF4(a0, i); procF4(a1, i + stride);
        procF4(a2, i + 2 * stride); procF4(a3, i + 3 * stride);
    }
    for (; i < V4; i += stride) { float4 a = row4[i]; procF4(a, i); }
    if (s == 0)
        for (int j = Vt + tid; j < V; j += NT2) emit(keyOf(row[j]), (unsigned)j);
}

// ---------------- K3: sort + top-k/top-p/sample/logprobs + outputs ----------
__global__ __launch_bounds__(NT3) void k_final(
    const float* __restrict__ logits,
    const float* __restrict__ temperature,
    const int* __restrict__ top_kv,
    const float* __restrict__ top_pv,
    const float* __restrict__ gumbel,
    const unsigned long long* __restrict__ candg,
    const int* __restrict__ cntA,
    float* __restrict__ out,
    int B, int V, int K, int capws)
{
    const int r = blockIdx.x;
    const int tid = threadIdx.x;
    const int lane = tid & 63;

    __shared__ unsigned long long cand[CAP];      // 32 KB; aliased as hist in fb
    __shared__ int scanI[NT3];
    __shared__ float varr[1024];
    __shared__ float Earr[1024];
    __shared__ float sfx[1024];
    __shared__ unsigned char flagArr[1024];
    __shared__ unsigned bitmap[64];
    __shared__ unsigned s_tlo;
    __shared__ unsigned s_prefix;
    __shared__ int s_cntgt, s_total, s_lvl;
    __shared__ int s_ncand, s_nkeep, s_rank, s_g0, s_g1;
    __shared__ unsigned long long s_amax;
    __shared__ float s_vs;

    unsigned* hist = (unsigned*)cand;

    const float* row = logits + (long long)r * V;
    const float* urow = gumbel + (long long)r * V;

    float traw = temperature[r];
    bool greedy = traw < 1e-5f;
    float t = greedy ? 1.0f : traw;               // ref: temp<eps -> divide by 1.0
    int k = top_kv[r];
    if (k < 1) k = 1;
    if (k > V) k = V;
    float p = top_pv[r];

    const float4* row4 = (const float4*)row;
    const int V4 = V >> 2;
    const int Vt = V4 << 2;
    const unsigned cpy = tid & 1u;

    const int ncand0 = cntA[r];
    const bool fb = (ncand0 < k) || (ncand0 > capws);
    int ncand;

    if (!fb) {
        // --------- main path: load candidates from workspace ---------
        const unsigned long long* cbase = candg + (long long)r * capws;
        for (int i = tid; i < ncand0; i += NT3) cand[i] = cbase[i];
        ncand = ncand0;
    } else {
        // --------- exact fallback: full 12-bit histogram + refine + compact ---
        for (int i = tid; i < BINS * 2; i += NT3) hist[i] = 0;
        __syncthreads();
        for (int i = tid; i < V4; i += NT3) {
            float4 l4 = row4[i];
            atomicAdd(&hist[((keyOf(l4.x) >> 20) << 1) | cpy], 1u);
            atomicAdd(&hist[((keyOf(l4.y) >> 20) << 1) | cpy], 1u);
            atomicAdd(&hist[((keyOf(l4.z) >> 20) << 1) | cpy], 1u);
            atomicAdd(&hist[((keyOf(l4.w) >> 20) << 1) | cpy], 1u);
        }
        for (int i = Vt + tid; i < V; i += NT3)
            atomicAdd(&hist[((keyOf(row[i]) >> 20) << 1) | cpy], 1u);
        __syncthreads();
        {
            int base = tid << 2;
            int cs = 0;
            #pragma unroll
            for (int j = 0; j < 4; ++j)
                cs += (int)(hist[(base + j) * 2] + hist[(base + j) * 2 + 1]);
            scanI[tid] = cs;
        }
        __syncthreads();
        for (int d = 1; d < NT3; d <<= 1) {
            int v = (tid + d < NT3) ? scanI[tid + d] : 0;
            __syncthreads();
            scanI[tid] += v;
            __syncthreads();
        }
        {
            int mine = scanI[tid];
            int above = (tid + 1 < NT3) ? scanI[tid + 1] : 0;
            if (mine >= k && above < k) {
                int base = tid << 2;
                int run = above;
                for (int b = base + 3; b >= base; --b) {
                    int mb = (int)(hist[b * 2] + hist[b * 2 + 1]);
                    if (run + mb >= k) {
                        s_prefix = (unsigned)b; s_cntgt = run;
                        s_total = run + mb; s_lvl = 0;
                        break;
                    }
                    run += mb;
                }
            }
        }
        for (int level = 1; level <= 2; ++level) {
            __syncthreads();
            if (s_total <= CAP) break;
            for (int i = tid; i < 512; i += NT3) hist[i] = 0;
            __syncthreads();
            unsigned pfx = s_prefix;
            const int msh = 32 - (12 + 8 * (level - 1));
            const int bsh = msh - 8;
            for (int i = tid; i < V4; i += NT3) {
                float4 l4 = row4[i];
                float vv[4] = { l4.x, l4.y, l4.z, l4.w };
                #pragma unroll
                for (int j = 0; j < 4; ++j) {
                    unsigned key = keyOf(vv[j]);
                    if ((key >> msh) == pfx)
                        atomicAdd(&hist[(((key >> bsh) & 255u) << 1) | cpy], 1u);
                }
            }
            for (int i = Vt + tid; i < V; i += NT3) {
                unsigned key = keyOf(row[i]);
                if ((key >> msh) == pfx)
                    atomicAdd(&hist[(((key >> bsh) & 255u) << 1) | cpy], 1u);
            }
            __syncthreads();
            if (tid == 0) {
                int run = s_cntgt;
                for (int b = 255; b >= 0; --b) {
                    int mb = (int)(hist[b * 2] + hist[b * 2 + 1]);
                    if (run + mb >= k) {
                        s_prefix = (pfx << 8) | (unsigned)b;
                        s_cntgt = run; s_total = run + mb;
                        break;
                    }
                    run += mb;
                }
                s_lvl = level;
            }
        }
        __syncthreads();
        if (tid == 0) { s_tlo = s_prefix << (20 - 8 * s_lvl); s_ncand = 0; }
        __syncthreads();
        for (int i = tid; i < V4; i += NT3) {
            float4 l4 = row4[i];
            float vv[4] = { l4.x, l4.y, l4.z, l4.w };
            #pragma unroll
            for (int j = 0; j < 4; ++j) {
                unsigned key = keyOf(vv[j]);
                bool pred = (key >= s_tlo);
                unsigned long long mask = __ballot(pred ? 1 : 0);
                if (mask) {
                    int leader = __ffsll(mask) - 1;
                    int cnt = __popcll(mask);
                    int base = 0;
                    if (lane == leader) base = atomicAdd(&s_ncand, cnt);
                    base = __shfl(base, leader);
                    if (pred) {
                        int pos = base + __popcll(mask & ((1ULL << lane) - 1ULL));
                        if (pos < CAP) {
                            unsigned gidx = (unsigned)(i * 4 + j);
                            cand[pos] = ((unsigned long long)key << 32) | (unsigned)(~gidx);
                        }
                    }
                }
            }
        }
        for (int j = Vt + tid; j < V; j += NT3) {
            unsigned key = keyOf(row[j]);
            bool pred = (key >= s_tlo);
            unsigned long long mask = __ballot(pred ? 1 : 0);
            if (mask) {
                int leader = __ffsll(mask) - 1;
                int cnt = __popcll(mask);
                int base = 0;
                if (lane == leader) base = atomicAdd(&s_ncand, cnt);
                base = __shfl(base, leader);
                if (pred) {
                    int pos = base + __popcll(mask & ((1ULL << lane) - 1ULL));
                    if (pos < CAP)
                        cand[pos] = ((unsigned long long)key << 32) | (unsigned)(~(unsigned)j);
                }
            }
        }
        __syncthreads();
        ncand = s_ncand; if (ncand > CAP) ncand = CAP;
        if (k > ncand) k = ncand;
    }
    __syncthreads();

    // ---------------- bitonic sort (descending) ----------------
    int P = 2; while (P < ncand) P <<= 1;
    for (int i = ncand + tid; i < P; i += NT3) cand[i] = 0ULL;
    __syncthreads();
    for (int size = 2; size <= P; size <<= 1) {
        for (int stride = size >> 1; stride > 0; stride >>= 1) {
            for (int i = tid; i < P; i += NT3) {
                int j = i ^ stride;
                if (j > i) {
                    unsigned long long a = cand[i], b = cand[j];
                    bool up = ((i & size) == 0);
                    bool sw = up ? (a < b) : (a > b);
                    if (sw) { cand[i] = b; cand[j] = a; }
                }
            }
            __syncthreads();
        }
    }

    // ---------------- divide once; top-k/top-p/sample ----------------
    for (int i = tid; i < 1024; i += NT3)
        varr[i] = (i < ncand) ? (valOfKey((unsigned)(cand[i] >> 32)) / t) : NEG_BIG;
    __syncthreads();

    const float m = varr[0];
    const float tkeyV = varr[k - 1];
    int ntop = k;
    while (ntop < ncand) {
        float vi = (ntop < 1024) ? varr[ntop]
                                 : (valOfKey((unsigned)(cand[ntop] >> 32)) / t);
        if (vi != tkeyV) break;
        ++ntop;
    }
    if (ntop > 1024) ntop = 1024;

    for (int i = tid; i < 1024; i += NT3) {
        float e = (i < ntop) ? expf(varr[i] - m) : 0.0f;
        Earr[i] = e;
        sfx[i] = e;
    }
    __syncthreads();
    for (int d = 1; d < 1024; d <<= 1) {          // inclusive suffix scan
        float t0 = (tid + d < 1024) ? sfx[tid + d] : 0.0f;
        __syncthreads();
        sfx[tid] += t0;
        __syncthreads();
    }
    const float Zp = sfx[0];
    const float cmp = 1.0f - p;
    if (tid == 0) { s_nkeep = 0; s_rank = 0; s_amax = 0ULL; }
    for (int i = tid; i < 64; i += NT3) bitmap[i] = 0;
    __syncthreads();
    {
        int local = 0;
        for (int i = tid; i < ntop; i += NT3)
            if (sfx[i] / Zp > cmp) local++;       // keep iff ascending-cum > 1-p
        if (local) atomicAdd(&s_nkeep, local);
    }
    __syncthreads();
    const int nkeep = s_nkeep;
    if (tid == 0) {                               // boundary v-tie group
        float vb = varr[nkeep - 1];
        int g0 = nkeep - 1;
        while (g0 > 0 && varr[g0 - 1] == vb) --g0;
        int g1 = nkeep;
        while (g1 < ntop && varr[g1] == vb) ++g1;
        s_g0 = g0; s_g1 = g1;
    }
    __syncthreads();
    const int g0 = s_g0, g1 = s_g1;
    const int mkeep = nkeep - g0;
    // kept members of boundary group = mkeep HIGHEST vocab indices
    for (int i = g0 + tid; i < g1; i += NT3) {
        unsigned gi = ~(unsigned)(cand[i] & 0xFFFFFFFFull);
        int rk = 0;
        for (int j = g0; j < g1; ++j) {
            unsigned gj = ~(unsigned)(cand[j] & 0xFFFFFFFFull);
            if (gj > gi) rk++;
        }
        flagArr[i] = (rk < mkeep) ? 1 : 0;
    }
    __syncthreads();

    const float Z2 = (nkeep < 1024) ? (Zp - sfx[nkeep]) : Zp;
    const float L = logf(Z2);

    for (int i = tid; i < g1; i += NT3) {
        if (i < g0 || flagArr[i]) {
            unsigned lo = (unsigned)(cand[i] & 0xFFFFFFFFull);
            unsigned gidx = ~lo;
            float u = urow[gidx];
            float q = -((u >= RMAX_F) ? RMAX_LOG_F : logf(u));
            float prob = Earr[i] / Z2;
            float ratio = greedy ? prob : (prob / q);
            unsigned long long comp = ((unsigned long long)__float_as_uint(ratio) << 32) | lo;
            atomicMax(&s_amax, comp);
            if (gidx < 2048) atomicOr(&bitmap[gidx >> 5], 1u << (gidx & 31));
        }
    }
    __syncthreads();
    const unsigned samp_lo = (unsigned)(s_amax & 0xFFFFFFFFull);
    const unsigned samp = ~samp_lo;
    for (int i = tid; i < ntop; i += NT3)
        if ((unsigned)(cand[i] & 0xFFFFFFFFull) == samp_lo) s_vs = varr[i];
    __syncthreads();
    const float lp_s = (s_vs - m) - L;
    {
        int local = 0;
        for (int i = tid; i < nkeep; i += NT3)
            if ((varr[i] - m) - L > lp_s) local++;
        if (local) atomicAdd(&s_rank, local);
    }
    __syncthreads();

    // ---------------- outputs ----------------
    if (tid == 0) {
        float* o_samp = out;
        float* o_idx  = out + B;
        float* o_lp   = out + B + (long long)B * (K + 1);
        float* o_rank = out + B + 2LL * B * (K + 1);
        long long rowo = (long long)r * (K + 1);

        o_samp[r] = (float)samp;
        o_idx[rowo] = (float)samp;
        o_lp[rowo] = lp_s;
        o_rank[r] = (float)s_rank;

        int ntk = (nkeep < K) ? nkeep : K;
        int slot = 0, i = 0;
        while (slot < ntk && i < g1) {
            float v = varr[i];
            int re = i + 1;
            while (re < g1 && varr[re] == v) ++re;   // v-run [i, re)
            long long last = -1;
            while (slot < ntk) {
                unsigned best = 0xFFFFFFFFu;
                for (int j = i; j < re; ++j) {
                    if (j >= g0 && !flagArr[j]) continue;
                    unsigned gj = ~(unsigned)(cand[j] & 0xFFFFFFFFull);
                    if ((long long)gj > last && gj < best) best = gj;
                }
                if (best == 0xFFFFFFFFu) break;
                o_idx[rowo + 1 + slot] = (float)best;
                o_lp[rowo + 1 + slot] = (v - m) - L;
                last = best; ++slot;
            }
            i = re;
        }
        if (nkeep < K) {
            // fillers: smallest non-kept vocab indices; finite "-inf" (see R1 note)
            int j = 0;
            for (int c = nkeep; c < K; ++c) {
                while (bitmap[j >> 5] & (1u << (j & 31))) ++j;
                o_idx[rowo + 1 + c] = (float)j;
                o_lp[rowo + 1 + c] = NEG_BIG;
                ++j;
            }
        }
    }
}

extern "C" void kernel_launch(void* const* d_in, const int* in_sizes, int n_in,
                              void* d_out, int out_size, void* d_ws, size_t ws_size,
                              hipStream_t stream) {
    const float* logits      = (const float*)d_in[0];
    const float* temperature = (const float*)d_in[1];
    const int*   top_k       = (const int*)d_in[2];
    const float* top_p       = (const float*)d_in[3];
    const float* gumbel      = (const float*)d_in[4];
    int B = in_sizes[1];
    int V = in_sizes[0] / B;
    int K = (out_size / B - 4) / 2;

    // workspace layout: cnt[B] | tlo[B] | cand[B][capws]
    int* cntA = (int*)d_ws;
    unsigned* tloA = (unsigned*)((char*)d_ws + (size_t)B * 4);
    size_t candOff = ((size_t)B * 8 + 7) & ~(size_t)7;
    size_t candBytes = (ws_size > candOff) ? (ws_size - candOff) : 0;
    int capws = (int)(candBytes / (8ull * (size_t)B));
    if (capws > CAP) capws = CAP;
    if (capws < 0) capws = 0;
    unsigned long long* candg = (unsigned long long*)((char*)d_ws + candOff);

    k_thresh<<<B, NT1, 0, stream>>>(logits, top_k, tloA, cntA, V);
    k_compact<<<B * G, NT2, 0, stream>>>(logits, tloA, cntA, candg, V, capws);
    k_final<<<B, NT3, 0, stream>>>(logits, temperature, top_k, top_p, gumbel,
                                   candg, cntA, (float*)d_out, B, V, K, capws);
}